// Round 2
// baseline (241.743 us; speedup 1.0000x reference)
//
#include <hip/hip_runtime.h>
#include <math.h>

#define D 256          // d_model
#define M 16           // num memory items
#define INV_TAU 10.0f
#define EPSN 1e-12f
#define MEM_STRIDE 260 // floats; 1040 B rows, 16B-aligned (retrieval copy)
#define NWAVES 4
#define BATCH 16       // rows per wave
#define ROWS_PER_BLOCK (NWAVES * BATCH) // 64
#define SIMW_STRIDE 20 // floats per sim row: 80 B

__device__ __forceinline__ float dot4(float4 a, float4 b) {
    return a.x * b.x + a.y * b.y + a.z * b.z + a.w * b.w;
}

// ---- round-0-validated DPP wave64 sum (VALU pipe, zero DS traffic) ----
template <int CTRL, int ROW_MASK, int BANK_MASK>
__device__ __forceinline__ float dpp_add(float x) {
    int xi = __builtin_bit_cast(int, x);
    int mi = __builtin_amdgcn_update_dpp(0, xi, CTRL, ROW_MASK, BANK_MASK, true);
    return x + __builtin_bit_cast(float, mi);
}
__device__ __forceinline__ float wave_sum(float x) {
    x = dpp_add<0x111, 0xf, 0xf>(x); // row_shr:1
    x = dpp_add<0x112, 0xf, 0xf>(x); // row_shr:2
    x = dpp_add<0x114, 0xf, 0xe>(x); // row_shr:4
    x = dpp_add<0x118, 0xf, 0xc>(x); // row_shr:8
    x = dpp_add<0x142, 0xa, 0xf>(x); // row_bcast:15 (rows 1,3)
    x = dpp_add<0x143, 0xc, 0xf>(x); // row_bcast:31 (rows 2,3)
    int t = __builtin_amdgcn_readlane(__builtin_bit_cast(int, x), 63);
    return __builtin_bit_cast(float, t);
}

// ---- multiplex butterfly reduce (validated __shfl_xor only) ----
// in : vals[m] = partial for memory m over this lane's 4 d-elements
// out: full 256-wide sum for m = bitrev4(lane & 15), on every lane
__device__ __forceinline__ float mux_reduce(float vals[16], int lane) {
    {   // mask 1: split m-range by 8 on lane bit 0
        const bool b = (lane & 1) != 0;
        #pragma unroll
        for (int j = 0; j < 8; ++j) {
            float send = b ? vals[j] : vals[j + 8];
            float recv = __shfl_xor(send, 1);
            vals[j] = (b ? vals[j + 8] : vals[j]) + recv;
        }
    }
    {   // mask 2: split by 4 on lane bit 1
        const bool b = (lane & 2) != 0;
        #pragma unroll
        for (int j = 0; j < 4; ++j) {
            float send = b ? vals[j] : vals[j + 4];
            float recv = __shfl_xor(send, 2);
            vals[j] = (b ? vals[j + 4] : vals[j]) + recv;
        }
    }
    {   // mask 4: split by 2 on lane bit 2
        const bool b = (lane & 4) != 0;
        #pragma unroll
        for (int j = 0; j < 2; ++j) {
            float send = b ? vals[j] : vals[j + 2];
            float recv = __shfl_xor(send, 4);
            vals[j] = (b ? vals[j + 2] : vals[j]) + recv;
        }
    }
    {   // mask 8: split by 1 on lane bit 3
        const bool b = (lane & 8) != 0;
        float send = b ? vals[0] : vals[1];
        float recv = __shfl_xor(send, 8);
        vals[0] = (b ? vals[1] : vals[0]) + recv;
    }
    float v = vals[0];
    v += __shfl_xor(v, 16);   // complete over d-chunk groups
    v += __shfl_xor(v, 32);
    return v;
}

__global__ __launch_bounds__(256, 4)
void epm_kernel(const float* __restrict__ q, const float* __restrict__ mem,
                float* __restrict__ ret_out, float* __restrict__ smax_out)
{
    __shared__ __align__(16) float mem_lds[M * MEM_STRIDE];
    __shared__ __align__(16) float simbuf[NWAVES][BATCH * SIMW_STRIDE]; // sims [r][m]
    __shared__ float nbuf[NWAVES][BATCH];                               // ||q||^2 per row
    __shared__ __align__(16) float wbuf[NWAVES][BATCH * 4];             // softmax weights
    __shared__ int   mbuf[NWAVES][BATCH];                               // packed top-4 idx

    const int tid  = threadIdx.x;
    const int wv   = tid >> 6;
    const int lane = tid & 63;

    // per-lane memory slice: memr2[m] = mem[m][4*lane .. 4*lane+3]
    float4 memr2[16];
    #pragma unroll
    for (int m = 0; m < M; ++m)
        memr2[m] = *(const float4*)&mem[m * D + 4 * lane];

    // stage raw memory rows into LDS (coalesced) for the retrieval gather
    {
        const float4* m4 = (const float4*)mem;
        #pragma unroll
        for (int p = 0; p < 4; ++p) {
            int vi  = p * 256 + tid;
            int row = vi >> 6;
            int col = (vi & 63) * 4;
            float4 v = m4[vi];
            *(float4*)&mem_lds[row * MEM_STRIDE + col] = v;
        }
    }
    __syncthreads();   // the only block-wide barrier

    // 1/||m|| for this lane's m = bitrev4(lane&15), via the SAME butterfly
    // (mapping is automatically consistent with the dot-phase output)
    float invm_l;
    {
        float nmv[16];
        #pragma unroll
        for (int m = 0; m < M; ++m) nmv[m] = dot4(memr2[m], memr2[m]);
        float nm = mux_reduce(nmv, lane);
        invm_l = 1.0f / fmaxf(sqrtf(nm), EPSN);
    }

    // bitrev4(lane&15): which memory this lane's reduced value belongs to
    const int brl = ((lane & 1) << 3) | ((lane & 2) << 1)
                  | ((lane & 4) >> 1) | ((lane & 8) >> 3);

    const int wave_row0 = blockIdx.x * ROWS_PER_BLOCK + wv * BATCH;
    float* simw = &simbuf[wv][0];
    const float4* q4 = (const float4*)q;

    // ================= dot phase: 16 rows, 4-deep prefetch =================
    float4 qpre[4];
    #pragma unroll
    for (int r = 0; r < 4; ++r)
        qpre[r] = q4[(size_t)(wave_row0 + r) * 64 + lane];

    #pragma unroll
    for (int r = 0; r < BATCH; ++r) {
        float4 qv = qpre[r & 3];
        if (r + 4 < BATCH)
            qpre[r & 3] = q4[(size_t)(wave_row0 + r + 4) * 64 + lane];

        // ||q||^2 via validated DPP wave_sum (wave-uniform result)
        float sq = wave_sum(dot4(qv, qv));
        if (lane == 0) nbuf[wv][r] = sq;

        // 16 independent 4-FMA partial-dot chains on own elements (no q sharing)
        float vals[16];
        #pragma unroll
        for (int m = 0; m < M; ++m) vals[m] = dot4(qv, memr2[m]);

        float v = mux_reduce(vals, lane);   // full dot for m = brl

        // scaled sim (inv_nq applied in top-k, row-uniform); 16 distinct banks
        if (lane < 16) simw[r * SIMW_STRIDE + brl] = v * invm_l * INV_TAU;
    }

    // ================= top-k phase: lane = row (round-0 verbatim) =================
    if (lane < BATCH) {
        const int r = lane;
        float ssq = nbuf[wv][r];
        float inv_nq = 1.0f / fmaxf(sqrtf(ssq), EPSN);

        float k0 = -INFINITY, k1 = -INFINITY, k2 = -INFINITY, k3 = -INFINITY;
        #pragma unroll
        for (int mm = 0; mm < M; ++mm) {
            float s = simw[r * SIMW_STRIDE + mm] * inv_nq;   // final sim
            int si = (__builtin_bit_cast(int, s) & ~15) | (15 - mm);
            float ks = __builtin_bit_cast(float, si);
            bool g0 = ks > k0, g1 = ks > k1, g2 = ks > k2, g3 = ks > k3;
            float n3 = g2 ? k2 : (g3 ? ks : k3);
            float n2 = g1 ? k1 : (g2 ? ks : k2);
            float n1 = g0 ? k0 : (g1 ? ks : k1);
            float n0 = g0 ? ks : k0;
            k0 = n0; k1 = n1; k2 = n2; k3 = n3;
        }
        int m0 = 15 - (__builtin_bit_cast(int, k0) & 15);
        int m1 = 15 - (__builtin_bit_cast(int, k1) & 15);
        int m2 = 15 - (__builtin_bit_cast(int, k2) & 15);
        int m3 = 15 - (__builtin_bit_cast(int, k3) & 15);

        float w0 = 1.0f;
        float w1 = __expf(k1 - k0);
        float w2 = __expf(k2 - k0);
        float w3 = __expf(k3 - k0);
        float invd = 1.0f / (w0 + w1 + w2 + w3);

        *(float4*)&wbuf[wv][r * 4] = make_float4(w0 * invd, w1 * invd, w2 * invd, w3 * invd);
        mbuf[wv][r] = m0 | (m1 << 8) | (m2 << 16) | (m3 << 24);

        smax_out[wave_row0 + r] = k0;   // sim_max (64B coalesced per wave)
    }

    // ================= retrieval phase: 16 rows (round-0 verbatim) =================
    #pragma unroll
    for (int r = 0; r < BATCH; ++r) {
        float4 w = *(const float4*)&wbuf[wv][r * 4]; // broadcast read
        int mp = mbuf[wv][r];                        // broadcast read
        float4 accv = make_float4(0.f, 0.f, 0.f, 0.f);
        #pragma unroll
        for (int k = 0; k < 4; ++k) {
            int mk = (mp >> (8 * k)) & 15;
            float wk = (k == 0) ? w.x : (k == 1) ? w.y : (k == 2) ? w.z : w.w;
            float4 mv = *(const float4*)&mem_lds[mk * MEM_STRIDE + 4 * lane];
            accv.x += wk * mv.x; accv.y += wk * mv.y;
            accv.z += wk * mv.z; accv.w += wk * mv.w;
        }
        ((float4*)ret_out)[(size_t)(wave_row0 + r) * 64 + lane] = accv;
    }
}

extern "C" void kernel_launch(void* const* d_in, const int* in_sizes, int n_in,
                              void* d_out, int out_size, void* d_ws, size_t ws_size,
                              hipStream_t stream) {
    const float* queries = (const float*)d_in[0];
    const float* memory  = (const float*)d_in[1];
    float* out = (float*)d_out;

    const int rows = in_sizes[0] / D;               // 131072
    float* ret_out  = out;                          // [rows, 256]
    float* smax_out = out + (size_t)rows * D;       // [rows]

    const int blocks = rows / ROWS_PER_BLOCK;       // 2048
    epm_kernel<<<blocks, 64 * NWAVES, 0, stream>>>(queries, memory, ret_out, smax_out);
}

// Round 3
// 236.981 us; speedup vs baseline: 1.0201x; 1.0201x over previous
//
#include <hip/hip_runtime.h>
#include <math.h>

#define D 256          // d_model
#define M 16           // num memory items
#define INV_TAU 10.0f
#define EPSN 1e-12f
#define MEM_STRIDE 260 // floats; 1040 B rows, 16B-aligned (retrieval copy)
#define NWAVES 4
#define BATCH 16       // rows per wave
#define ROWS_PER_BLOCK (NWAVES * BATCH) // 64
#define SIMW_STRIDE 20 // floats per sim row: 80 B

__device__ __forceinline__ float dot4(float4 a, float4 b) {
    return a.x * b.x + a.y * b.y + a.z * b.z + a.w * b.w;
}

// ---- validated DPP wave64 sum (VALU pipe, zero DS traffic) ----
template <int CTRL, int ROW_MASK, int BANK_MASK>
__device__ __forceinline__ float dpp_add(float x) {
    int xi = __builtin_bit_cast(int, x);
    int mi = __builtin_amdgcn_update_dpp(0, xi, CTRL, ROW_MASK, BANK_MASK, true);
    return x + __builtin_bit_cast(float, mi);
}
__device__ __forceinline__ float wave_sum(float x) {
    x = dpp_add<0x111, 0xf, 0xf>(x); // row_shr:1
    x = dpp_add<0x112, 0xf, 0xf>(x); // row_shr:2
    x = dpp_add<0x114, 0xf, 0xe>(x); // row_shr:4
    x = dpp_add<0x118, 0xf, 0xc>(x); // row_shr:8
    x = dpp_add<0x142, 0xa, 0xf>(x); // row_bcast:15 (rows 1,3)
    x = dpp_add<0x143, 0xc, 0xf>(x); // row_bcast:31 (rows 2,3)
    int t = __builtin_amdgcn_readlane(__builtin_bit_cast(int, x), 63);
    return __builtin_bit_cast(float, t);
}

// ---- multiplex butterfly reduce (validated in round 2) ----
// in : vals[m] = partial for memory m over this lane's 4 d-elements
// out: full 256-wide sum for m = bitrev4(lane & 15), on every lane
__device__ __forceinline__ float mux_reduce(float vals[16], int lane) {
    {   // mask 1: split m-range by 8 on lane bit 0
        const bool b = (lane & 1) != 0;
        #pragma unroll
        for (int j = 0; j < 8; ++j) {
            float send = b ? vals[j] : vals[j + 8];
            float recv = __shfl_xor(send, 1);
            vals[j] = (b ? vals[j + 8] : vals[j]) + recv;
        }
    }
    {   // mask 2: split by 4 on lane bit 1
        const bool b = (lane & 2) != 0;
        #pragma unroll
        for (int j = 0; j < 4; ++j) {
            float send = b ? vals[j] : vals[j + 4];
            float recv = __shfl_xor(send, 2);
            vals[j] = (b ? vals[j + 4] : vals[j]) + recv;
        }
    }
    {   // mask 4: split by 2 on lane bit 2
        const bool b = (lane & 4) != 0;
        #pragma unroll
        for (int j = 0; j < 2; ++j) {
            float send = b ? vals[j] : vals[j + 2];
            float recv = __shfl_xor(send, 4);
            vals[j] = (b ? vals[j + 2] : vals[j]) + recv;
        }
    }
    {   // mask 8: split by 1 on lane bit 3
        const bool b = (lane & 8) != 0;
        float send = b ? vals[0] : vals[1];
        float recv = __shfl_xor(send, 8);
        vals[0] = (b ? vals[1] : vals[0]) + recv;
    }
    float v = vals[0];
    v += __shfl_xor(v, 16);   // complete over d-chunk groups
    v += __shfl_xor(v, 32);
    return v;
}

// (256, 2): cap 256 VGPRs so memr2[16]+vals[16]+qpre[4] live in registers.
// Round-2's (256, 4) made the backend stop at 64 VGPRs and spill ~46 MB
// to scratch (WRITE_SIZE 135.7 -> 166.4 MB) — the measured regression.
__global__ __launch_bounds__(256, 2)
void epm_kernel(const float* __restrict__ q, const float* __restrict__ mem,
                float* __restrict__ ret_out, float* __restrict__ smax_out)
{
    __shared__ __align__(16) float mem_lds[M * MEM_STRIDE];
    __shared__ __align__(16) float simbuf[NWAVES][BATCH * SIMW_STRIDE]; // final sims [r][m]
    __shared__ __align__(16) float wbuf[NWAVES][BATCH * 4];             // softmax weights
    __shared__ int   mbuf[NWAVES][BATCH];                               // packed top-4 idx

    const int tid  = threadIdx.x;
    const int wv   = tid >> 6;
    const int lane = tid & 63;

    // per-lane memory slice: memr2[m] = mem[m][4*lane .. 4*lane+3]
    float4 memr2[16];
    #pragma unroll
    for (int m = 0; m < M; ++m)
        memr2[m] = *(const float4*)&mem[m * D + 4 * lane];

    // stage raw memory rows into LDS (coalesced) for the retrieval gather
    {
        const float4* m4 = (const float4*)mem;
        #pragma unroll
        for (int p = 0; p < 4; ++p) {
            int vi  = p * 256 + tid;
            int row = vi >> 6;
            int col = (vi & 63) * 4;
            float4 v = m4[vi];
            *(float4*)&mem_lds[row * MEM_STRIDE + col] = v;
        }
    }
    __syncthreads();   // the only block-wide barrier

    // 1/||m|| for this lane's m = bitrev4(lane&15), via the SAME butterfly
    float invm_l;
    {
        float nmv[16];
        #pragma unroll
        for (int m = 0; m < M; ++m) nmv[m] = dot4(memr2[m], memr2[m]);
        float nm = mux_reduce(nmv, lane);
        invm_l = 1.0f / fmaxf(sqrtf(nm), EPSN);
    }

    const int wave_row0 = blockIdx.x * ROWS_PER_BLOCK + wv * BATCH;
    float* simw = &simbuf[wv][0];
    const float4* q4 = (const float4*)q;

    // ================= dot phase: 16 rows, 4-deep prefetch =================
    float4 qpre[4];
    #pragma unroll
    for (int r = 0; r < 4; ++r)
        qpre[r] = q4[(size_t)(wave_row0 + r) * 64 + lane];

    #pragma unroll
    for (int r = 0; r < BATCH; ++r) {
        float4 qv = qpre[r & 3];
        if (r + 4 < BATCH)
            qpre[r & 3] = q4[(size_t)(wave_row0 + r + 4) * 64 + lane];

        // ||q||^2 via DPP wave_sum (wave-uniform) -> fold 1/||q||/tau here
        float sq = wave_sum(dot4(qv, qv));
        float tsc = INV_TAU / fmaxf(sqrtf(sq), EPSN);

        // 16 independent 4-FMA partial-dot chains on own elements
        float vals[16];
        #pragma unroll
        for (int m = 0; m < M; ++m) vals[m] = dot4(qv, memr2[m]);

        float v = mux_reduce(vals, lane);   // full dot for m = bitrev4(lane&15)

        // FINAL sim stored (both norms + tau applied); 16 distinct banks
        if (lane < 16) {
            const int brl = ((lane & 1) << 3) | ((lane & 2) << 1)
                          | ((lane & 4) >> 1) | ((lane & 8) >> 3);
            simw[r * SIMW_STRIDE + brl] = v * invm_l * tsc;
        }
    }

    // ================= top-k phase: lane = row =================
    if (lane < BATCH) {
        const int r = lane;

        float k0 = -INFINITY, k1 = -INFINITY, k2 = -INFINITY, k3 = -INFINITY;
        #pragma unroll
        for (int mm = 0; mm < M; ++mm) {
            float s = simw[r * SIMW_STRIDE + mm];            // already final
            int si = (__builtin_bit_cast(int, s) & ~15) | (15 - mm);
            float ks = __builtin_bit_cast(float, si);
            bool g0 = ks > k0, g1 = ks > k1, g2 = ks > k2, g3 = ks > k3;
            float n3 = g2 ? k2 : (g3 ? ks : k3);
            float n2 = g1 ? k1 : (g2 ? ks : k2);
            float n1 = g0 ? k0 : (g1 ? ks : k1);
            float n0 = g0 ? ks : k0;
            k0 = n0; k1 = n1; k2 = n2; k3 = n3;
        }
        int m0 = 15 - (__builtin_bit_cast(int, k0) & 15);
        int m1 = 15 - (__builtin_bit_cast(int, k1) & 15);
        int m2 = 15 - (__builtin_bit_cast(int, k2) & 15);
        int m3 = 15 - (__builtin_bit_cast(int, k3) & 15);

        float w0 = 1.0f;
        float w1 = __expf(k1 - k0);
        float w2 = __expf(k2 - k0);
        float w3 = __expf(k3 - k0);
        float invd = 1.0f / (w0 + w1 + w2 + w3);

        *(float4*)&wbuf[wv][r * 4] = make_float4(w0 * invd, w1 * invd, w2 * invd, w3 * invd);
        mbuf[wv][r] = m0 | (m1 << 8) | (m2 << 16) | (m3 << 24);

        smax_out[wave_row0 + r] = k0;   // sim_max (64B coalesced per wave)
    }

    // ================= retrieval phase: 16 rows =================
    #pragma unroll
    for (int r = 0; r < BATCH; ++r) {
        float4 w = *(const float4*)&wbuf[wv][r * 4]; // broadcast read
        int mp = mbuf[wv][r];                        // broadcast read
        float4 accv = make_float4(0.f, 0.f, 0.f, 0.f);
        #pragma unroll
        for (int k = 0; k < 4; ++k) {
            int mk = (mp >> (8 * k)) & 15;
            float wk = (k == 0) ? w.x : (k == 1) ? w.y : (k == 2) ? w.z : w.w;
            float4 mv = *(const float4*)&mem_lds[mk * MEM_STRIDE + 4 * lane];
            accv.x += wk * mv.x; accv.y += wk * mv.y;
            accv.z += wk * mv.z; accv.w += wk * mv.w;
        }
        ((float4*)ret_out)[(size_t)(wave_row0 + r) * 64 + lane] = accv;
    }
}

extern "C" void kernel_launch(void* const* d_in, const int* in_sizes, int n_in,
                              void* d_out, int out_size, void* d_ws, size_t ws_size,
                              hipStream_t stream) {
    const float* queries = (const float*)d_in[0];
    const float* memory  = (const float*)d_in[1];
    float* out = (float*)d_out;

    const int rows = in_sizes[0] / D;               // 131072
    float* ret_out  = out;                          // [rows, 256]
    float* smax_out = out + (size_t)rows * D;       // [rows]

    const int blocks = rows / ROWS_PER_BLOCK;       // 2048
    epm_kernel<<<blocks, 64 * NWAVES, 0, stream>>>(queries, memory, ret_out, smax_out);
}